// Round 6
// baseline (189.033 us; speedup 1.0000x reference)
//
#include <hip/hip_runtime.h>

// B=64, L=512, D=768, V=100
// summed[b,l,:] = w0s * pooler[b,l,:] + w1s * xt[b,:]
//   xt[b,d] = e0*W[0,d] + e1*W[1,d] + b_dense[d],  (e0,e1) = emb_table[ids[b]]
//   s00 = p.p (row), s01 = p.xt (row), s11 = xt.xt (per b); S0 = sum p, S1 = sum xt
//   out = gamma*(a*p + (c*xt - m)) + beta,  a=w0s*rstd, c=w1s*rstd, m=mean*rstd
//
// History:
// R1/R2: 4-wave blocks + NT stores.                           (~58-62 us kernel)
// R3: 4 rows/wave hoisting — REGRESSED (~65): serialized row loop.
// R4/R5: loads-up-front + launch_bounds(256,4) — NEUTRAL. VGPR stuck at 64:
//   hipcc sinks/remats loads rather than hold a 48-VGPR tile across the
//   butterfly+exp. (Theory later falsified as the *cause* of the floor.)
// R6: two-pass via d_ws — REGRESSED (~71): +66% traffic, same floor.
// R7: LDS stash of p (own-wave slice, no barrier) — recovered best (~58)
//   but floor unmoved => load-side serialization is NOT the limiter.
// Common feature of ALL 57-66us variants: __builtin_nontemporal_store.
//   58us ~= 98MB / 1.7 TB/s; fill kernel does 6.8 TB/s with PLAIN stores.
//   Theory: gfx950 NT stores drain via a slow L2-bypass streaming path;
//   store backpressure caps the kernel (masquerading as latency-boundness).
// R8: single variable vs R7 — plain cached float4 stores (full-line,
//   wave-contiguous 1KB => no RFO). Predict kernel 58 -> 32-40us.

constexpr int Bc = 64;
constexpr int Lc = 512;
constexpr int Dc = 768;            // 192 float4 = 3 float4 per lane (wave64)
constexpr int NF4 = Dc / 4;        // 192
constexpr float LN_EPS = 1e-6f;
constexpr int WPB = 4;             // waves per block
constexpr int RPW = 2;             // rows per wave (2 | 512 -> same b per wave)
constexpr int RPB = WPB * RPW;     // 8 rows per block

__global__ __launch_bounds__(64 * WPB) void hier_attn_ln_kernel(
    const int*   __restrict__ ids,        // (B,1)
    const float* __restrict__ pooler,     // (B,L,D)
    const float* __restrict__ emb_table,  // (V,2)
    const float* __restrict__ W,          // (2,D)
    const float* __restrict__ bvec,       // (D,)
    const float* __restrict__ gamma,      // (D,)
    const float* __restrict__ beta,      // (D,)
    float*       __restrict__ out)        // (B,L,D)
{
    // Per-wave private slices; written and read by the same wave only ->
    // no __syncthreads anywhere (no inter-wave lockstep).
    __shared__ float4 tile[WPB][RPW][NF4];          // 4*2*192*16 B = 24 KB

    const int wave = threadIdx.x >> 6;
    const int lane = threadIdx.x & 63;
    const int row0 = blockIdx.x * RPB + wave * RPW;
    const int b    = row0 >> 9;                     // L = 512; 8 | 512

    const float4* W0_4 = (const float4*)W;
    const float4* W1_4 = (const float4*)(W + Dc);
    const float4* b_4  = (const float4*)bvec;
    const float4* g_4  = (const float4*)gamma;
    const float4* be_4 = (const float4*)beta;

    const int id = ids[b];
    const float e0 = emb_table[id * 2 + 0];
    const float e1 = emb_table[id * 2 + 1];

    // ---- xt (broadcast cache-hot loads) + per-b partials ----
    float4 xt[3];
    float s11 = 0.f, S1 = 0.f;
#pragma unroll
    for (int j = 0; j < 3; ++j) {
        const int i4 = lane + j * 64;
        float4 w0 = W0_4[i4], w1 = W1_4[i4], bd = b_4[i4];
        float4 x;
        x.x = fmaf(e0, w0.x, fmaf(e1, w1.x, bd.x));
        x.y = fmaf(e0, w0.y, fmaf(e1, w1.y, bd.y));
        x.z = fmaf(e0, w0.z, fmaf(e1, w1.z, bd.z));
        x.w = fmaf(e0, w0.w, fmaf(e1, w1.w, bd.w));
        xt[j] = x;
        s11 += x.x*x.x + x.y*x.y + x.z*x.z + x.w*x.w;
        S1  += x.x + x.y + x.z + x.w;
    }

    // ---- pooler loads: consumed IMMEDIATELY (ds_write + 3 FMAs), value dies.
    //      Scheduler is free to keep all 6 loads in flight. ----
    const float4* p_base = (const float4*)(pooler + (size_t)row0 * Dc);
    float s00[RPW], s01[RPW], S0[RPW];
#pragma unroll
    for (int r = 0; r < RPW; ++r) {
        float a0 = 0.f, a1 = 0.f, a2 = 0.f;
#pragma unroll
        for (int j = 0; j < 3; ++j) {
            const int i4 = lane + j * 64;
            const float4 p = p_base[r * NF4 + i4];
            tile[wave][r][i4] = p;                   // ds_write_b128, own slice
            a0 += p.x*p.x + p.y*p.y + p.z*p.z + p.w*p.w;
            a1 += p.x*xt[j].x + p.y*xt[j].y + p.z*xt[j].z + p.w*xt[j].w;
            a2 += p.x + p.y + p.z + p.w;
        }
        s00[r] = a0; s01[r] = a1; S0[r] = a2;
    }

    // ---- joint butterfly: 6 steps, 8 interleaved chains ----
#pragma unroll
    for (int off = 32; off > 0; off >>= 1) {
        s11 += __shfl_xor(s11, off);
        S1  += __shfl_xor(S1,  off);
#pragma unroll
        for (int r = 0; r < RPW; ++r) {
            s00[r] += __shfl_xor(s00[r], off);
            s01[r] += __shfl_xor(s01[r], off);
            S0[r]  += __shfl_xor(S0[r],  off);
        }
    }

    // ---- gamma/beta (cache-hot broadcast), latency hidden under softmax ----
    float4 gm[3], bt[3];
#pragma unroll
    for (int j = 0; j < 3; ++j) {
        gm[j] = g_4[lane + j * 64];
        bt[j] = be_4[lane + j * 64];
    }

    // ---- per-row softmax + LN scalars (static indices only) ----
    const float invD = 1.f / (float)Dc;
    float ascale[RPW], cscale[RPW], mshift[RPW];
#pragma unroll
    for (int r = 0; r < RPW; ++r) {
        // Two 2-way softmaxes (max-subtracted: s00 ~ O(768), naive exp overflows).
        const float m0  = fmaxf(s00[r], s01[r]);
        const float a00 = __expf(s00[r] - m0);
        const float a01 = __expf(s01[r] - m0);
        const float r0  = 1.f / (a00 + a01);
        const float m1  = fmaxf(s01[r], s11);
        const float a10 = __expf(s01[r] - m1);
        const float a11 = __expf(s11 - m1);
        const float r1  = 1.f / (a10 + a11);
        const float w0s = a00 * r0 + a10 * r1;       // weight on pooler
        const float w1s = a01 * r0 + a11 * r1;       // weight on xt

        const float mean = (w0s * S0[r] + w1s * S1) * invD;
        const float ex2  = (w0s*w0s*s00[r] + 2.f*w0s*w1s*s01[r] + w1s*w1s*s11) * invD;
        const float var  = ex2 - mean * mean;
        const float rstd = rsqrtf(var + LN_EPS);

        ascale[r] = w0s * rstd;
        cscale[r] = w1s * rstd;
        mshift[r] = mean * rstd;
    }

    // ---- epilogue: re-read p from own LDS slice, triad, PLAIN cached store
    //      (the single variable vs R7: no nontemporal hint) ----
    float4* o_base = (float4*)(out + (size_t)row0 * Dc);
#pragma unroll
    for (int r = 0; r < RPW; ++r) {
        const float a = ascale[r], c = cscale[r], m = mshift[r];
        float4* orow = o_base + (size_t)r * NF4;
#pragma unroll
        for (int j = 0; j < 3; ++j) {
            const int i4 = lane + j * 64;
            const float4 p = tile[wave][r][i4];
            float4 o;
            o.x = fmaf(gm[j].x, fmaf(a, p.x, fmaf(c, xt[j].x, -m)), bt[j].x);
            o.y = fmaf(gm[j].y, fmaf(a, p.y, fmaf(c, xt[j].y, -m)), bt[j].y);
            o.z = fmaf(gm[j].z, fmaf(a, p.z, fmaf(c, xt[j].z, -m)), bt[j].z);
            o.w = fmaf(gm[j].w, fmaf(a, p.w, fmaf(c, xt[j].w, -m)), bt[j].w);
            orow[i4] = o;
        }
    }
}

extern "C" void kernel_launch(void* const* d_in, const int* in_sizes, int n_in,
                              void* d_out, int out_size, void* d_ws, size_t ws_size,
                              hipStream_t stream) {
    const int*   ids       = (const int*)  d_in[0];
    const float* pooler    = (const float*)d_in[1];
    const float* emb_table = (const float*)d_in[2];
    const float* W_dense   = (const float*)d_in[3];
    const float* b_dense   = (const float*)d_in[4];
    const float* gamma     = (const float*)d_in[5];
    const float* beta      = (const float*)d_in[6];
    float* out = (float*)d_out;

    const int nrows = Bc * Lc;                      // 32768
    hipLaunchKernelGGL(hier_attn_ln_kernel,
                       dim3(nrows / RPB), dim3(64 * WPB),   // 4096 blocks
                       0, stream,
                       ids, pooler, emb_table, W_dense, b_dense, gamma, beta, out);
}